// Round 1
// baseline (1225.891 us; speedup 1.0000x reference)
//
#include <hip/hip_runtime.h>

constexpr int N_NODES = 50000;
constexpr int N_EDGES = 800000;
constexpr int ND  = 32;
constexpr int ED  = 16;
constexpr int HID = 96;
constexpr int NH  = 4;
constexpr int CH  = 24;
constexpr int NLAYER = 3;

// ---------------- CSR build (by dst), once per call ----------------
__global__ void k_count_deg(const int* __restrict__ dst, int* __restrict__ deg) {
    int e = blockIdx.x * 256 + threadIdx.x;
    if (e < N_EDGES) atomicAdd(&deg[dst[e]], 1);
}

__global__ void k_scan_block(const int* __restrict__ deg, int* __restrict__ rowptr,
                             int* __restrict__ bsum) {
    __shared__ int s[256];
    int i = blockIdx.x * 256 + threadIdx.x;
    int v = (i < N_NODES) ? deg[i] : 0;
    s[threadIdx.x] = v;
    __syncthreads();
    for (int off = 1; off < 256; off <<= 1) {
        int t = (threadIdx.x >= off) ? s[threadIdx.x - off] : 0;
        __syncthreads();
        s[threadIdx.x] += t;
        __syncthreads();
    }
    if (i < N_NODES) rowptr[i] = s[threadIdx.x] - v;   // exclusive within block
    if (threadIdx.x == 255) bsum[blockIdx.x] = s[255]; // block total
}

__global__ void k_scan_bsum(int* __restrict__ bsum, int nb) {
    __shared__ int s[256];
    int t = threadIdx.x;
    int v = (t < nb) ? bsum[t] : 0;
    s[t] = v;
    __syncthreads();
    for (int off = 1; off < 256; off <<= 1) {
        int tv = (t >= off) ? s[t - off] : 0;
        __syncthreads();
        s[t] += tv;
        __syncthreads();
    }
    if (t < nb) bsum[t] = s[t] - v;  // exclusive block prefix
}

__global__ void k_scan_add(int* __restrict__ rowptr, const int* __restrict__ bsum) {
    int i = blockIdx.x * 256 + threadIdx.x;
    if (i < N_NODES) rowptr[i] += bsum[blockIdx.x];
    if (i == 0) rowptr[N_NODES] = N_EDGES;
}

__global__ void k_scatter(const int* __restrict__ src, const int* __restrict__ dst,
                          const int* __restrict__ rowptr, int* __restrict__ fill,
                          int2* __restrict__ csr) {
    int e = blockIdx.x * 256 + threadIdx.x;
    if (e >= N_EDGES) return;
    int d = dst[e];
    int pos = rowptr[d] + atomicAdd(&fill[d], 1);
    csr[pos] = make_int2(src[e], e);
}

// ---------------- proj: h = x @ proj_w + proj_b  (K=32) ----------------
__global__ __launch_bounds__(192) void k_proj(const float* __restrict__ x,
                                              const float* __restrict__ pw,
                                              const float* __restrict__ pb,
                                              float* __restrict__ h) {
    int t = threadIdx.x;
    int c = t % 96, half = t / 96;
    float wreg[ND];
#pragma unroll
    for (int k = 0; k < ND; k++) wreg[k] = pw[k * HID + c];
    float b = pb[c];
    int n0 = blockIdx.x * 16 + half * 8;
    for (int i = 0; i < 8; i++) {
        int n = n0 + i;
        const float4* x4 = (const float4*)(x + (size_t)n * ND);
        float acc = b;
#pragma unroll
        for (int k4 = 0; k4 < ND / 4; k4++) {
            float4 v = x4[k4];
            acc += v.x * wreg[4 * k4] + v.y * wreg[4 * k4 + 1] +
                   v.z * wreg[4 * k4 + 2] + v.w * wreg[4 * k4 + 3];
        }
        h[(size_t)n * HID + c] = acc;
    }
}

// ---------------- xl = h@Wl+bl, xr = h@Wr+br (fused, K=96) ----------------
__global__ __launch_bounds__(192) void k_lin_lr(const float* __restrict__ h,
                                                const float* __restrict__ Wl,
                                                const float* __restrict__ bl,
                                                const float* __restrict__ Wr,
                                                const float* __restrict__ br,
                                                float* __restrict__ xl,
                                                float* __restrict__ xr) {
    int t = threadIdx.x;
    int c = t % 96, half = t / 96;
    const float* W = half ? Wr : Wl;
    float b = half ? br[c] : bl[c];
    float* out = half ? xr : xl;
    float wreg[HID];
#pragma unroll
    for (int k = 0; k < HID; k++) wreg[k] = W[k * HID + c];
    int n0 = blockIdx.x * 16;
    for (int i = 0; i < 16; i++) {
        int n = n0 + i;
        const float4* h4 = (const float4*)(h + (size_t)n * HID);
        float acc = b;
#pragma unroll
        for (int k4 = 0; k4 < HID / 4; k4++) {
            float4 v = h4[k4];
            acc += v.x * wreg[4 * k4] + v.y * wreg[4 * k4 + 1] +
                   v.z * wreg[4 * k4 + 2] + v.w * wreg[4 * k4 + 3];
        }
        out[(size_t)n * HID + c] = acc;
    }
}

// ------- fused GATv2 edge pass + softmax + aggregate + residual + LN -------
// 32-lane group per node (8 nodes / 256-thread block); lane owns channels 3t..3t+2
// (all within one head since head boundaries are multiples of 24 = 8 lanes).
// We kept in registers (48 vals/lane, fixed across edges). No segment_max:
// logits are O(0.2), unshifted exp is safe and mathematically identical.
__global__ __launch_bounds__(256) void k_aggregate(
    const float* __restrict__ xl, const float* __restrict__ xr,
    const float* __restrict__ eattr, const int* __restrict__ rowptr,
    const int2* __restrict__ csr, const float* __restrict__ WeL,
    const float* __restrict__ attL, const float* __restrict__ convb,
    const float* __restrict__ lng, const float* __restrict__ lnb,
    float* __restrict__ h) {
    int t = threadIdx.x;
    int lane = t & 31, grp = t >> 5;
    int node = blockIdx.x * 8 + grp;
    if (node >= N_NODES) return;
    int c0 = lane * 3;

    float we[3 * ED];
#pragma unroll
    for (int k = 0; k < ED; k++) {
#pragma unroll
        for (int j = 0; j < 3; j++) we[k * 3 + j] = WeL[k * HID + c0 + j];
    }
    float attv0 = attL[c0], attv1 = attL[c0 + 1], attv2 = attL[c0 + 2];
    size_t nbase = (size_t)node * HID + c0;
    float xrv0 = xr[nbase], xrv1 = xr[nbase + 1], xrv2 = xr[nbase + 2];

    float num0 = 0.f, num1 = 0.f, num2 = 0.f, den = 0.f;
    int beg = rowptr[node], end = rowptr[node + 1];
    for (int p = beg; p < end; ++p) {
        int2 se = csr[p];
        const float4* ea4 = (const float4*)(eattr + (size_t)se.y * ED);
        float4 a0 = ea4[0], a1 = ea4[1], a2 = ea4[2], a3 = ea4[3];
        float ea[16] = {a0.x, a0.y, a0.z, a0.w, a1.x, a1.y, a1.z, a1.w,
                        a2.x, a2.y, a2.z, a2.w, a3.x, a3.y, a3.z, a3.w};
        const float* xlr = xl + (size_t)se.x * HID + c0;
        float x0 = xlr[0], x1 = xlr[1], x2 = xlr[2];
        float e0 = 0.f, e1 = 0.f, e2 = 0.f;
#pragma unroll
        for (int k = 0; k < ED; k++) {
            e0 += ea[k] * we[k * 3 + 0];
            e1 += ea[k] * we[k * 3 + 1];
            e2 += ea[k] * we[k * 3 + 2];
        }
        float z0 = x0 + xrv0 + e0; z0 = z0 > 0.f ? z0 : 0.2f * z0;
        float z1 = x1 + xrv1 + e1; z1 = z1 > 0.f ? z1 : 0.2f * z1;
        float z2 = x2 + xrv2 + e2; z2 = z2 > 0.f ? z2 : 0.2f * z2;
        float lg = z0 * attv0 + z1 * attv1 + z2 * attv2;
        lg += __shfl_xor(lg, 1);
        lg += __shfl_xor(lg, 2);
        lg += __shfl_xor(lg, 4);   // sum over the head's 8 lanes (24 channels)
        float ev = __expf(lg);
        den += ev;
        num0 += ev * x0; num1 += ev * x1; num2 += ev * x2;
    }
    float inv = 1.f / (den + 1e-16f);
    float v0 = h[nbase]     + num0 * inv + convb[c0];
    float v1 = h[nbase + 1] + num1 * inv + convb[c0 + 1];
    float v2 = h[nbase + 2] + num2 * inv + convb[c0 + 2];
    // LayerNorm over 96 channels = 32 lanes x 3
    float sm = v0 + v1 + v2;
    sm += __shfl_xor(sm, 1);  sm += __shfl_xor(sm, 2);  sm += __shfl_xor(sm, 4);
    sm += __shfl_xor(sm, 8);  sm += __shfl_xor(sm, 16);
    float mu = sm * (1.f / 96.f);
    float d0 = v0 - mu, d1 = v1 - mu, d2 = v2 - mu;
    float sv = d0 * d0 + d1 * d1 + d2 * d2;
    sv += __shfl_xor(sv, 1);  sv += __shfl_xor(sv, 2);  sv += __shfl_xor(sv, 4);
    sv += __shfl_xor(sv, 8);  sv += __shfl_xor(sv, 16);
    float rstd = rsqrtf(sv * (1.f / 96.f) + 1e-5f);
    h[nbase]     = d0 * rstd * lng[c0]     + lnb[c0];
    h[nbase + 1] = d1 * rstd * lng[c0 + 1] + lnb[c0 + 1];
    h[nbase + 2] = d2 * rstd * lng[c0 + 2] + lnb[c0 + 2];
}

// ---------------- head: gelu(h@W1+b1)@W2+b2 ----------------
__global__ __launch_bounds__(256) void k_head(const float* __restrict__ h,
                                              const float* __restrict__ W1,
                                              const float* __restrict__ b1,
                                              const float* __restrict__ W2,
                                              const float* __restrict__ b2,
                                              float* __restrict__ out) {
    int n = blockIdx.x * 256 + threadIdx.x;
    if (n >= N_NODES) return;
    float hr[HID];
    const float4* h4 = (const float4*)(h + (size_t)n * HID);
#pragma unroll
    for (int i = 0; i < HID / 4; i++) {
        float4 v = h4[i];
        hr[4 * i] = v.x; hr[4 * i + 1] = v.y; hr[4 * i + 2] = v.z; hr[4 * i + 3] = v.w;
    }
    float y = b2[0];
    for (int j0 = 0; j0 < 48; j0 += 4) {
        float4 acc = make_float4(b1[j0], b1[j0 + 1], b1[j0 + 2], b1[j0 + 3]);
#pragma unroll
        for (int k = 0; k < HID; k++) {
            float4 w = *(const float4*)(W1 + k * 48 + j0);
            acc.x += hr[k] * w.x; acc.y += hr[k] * w.y;
            acc.z += hr[k] * w.z; acc.w += hr[k] * w.w;
        }
        const float inv_sqrt2 = 0.70710678118654752f;
        float g0 = 0.5f * acc.x * (1.f + erff(acc.x * inv_sqrt2));
        float g1 = 0.5f * acc.y * (1.f + erff(acc.y * inv_sqrt2));
        float g2 = 0.5f * acc.z * (1.f + erff(acc.z * inv_sqrt2));
        float g3 = 0.5f * acc.w * (1.f + erff(acc.w * inv_sqrt2));
        y += g0 * W2[j0] + g1 * W2[j0 + 1] + g2 * W2[j0 + 2] + g3 * W2[j0 + 3];
    }
    out[n] = y;
}

extern "C" void kernel_launch(void* const* d_in, const int* in_sizes, int n_in,
                              void* d_out, int out_size, void* d_ws, size_t ws_size,
                              hipStream_t stream) {
    const float* x       = (const float*)d_in[0];
    const int*   eidx    = (const int*)  d_in[1];
    const float* eattr   = (const float*)d_in[2];
    const float* proj_w  = (const float*)d_in[3];
    const float* proj_b  = (const float*)d_in[4];
    const float* lin_l_w = (const float*)d_in[5];
    const float* lin_l_b = (const float*)d_in[6];
    const float* lin_r_w = (const float*)d_in[7];
    const float* lin_r_b = (const float*)d_in[8];
    const float* lin_e_w = (const float*)d_in[9];
    const float* att     = (const float*)d_in[10];
    const float* conv_b  = (const float*)d_in[11];
    const float* ln_g    = (const float*)d_in[12];
    const float* ln_b    = (const float*)d_in[13];
    const float* head_w1 = (const float*)d_in[14];
    const float* head_b1 = (const float*)d_in[15];
    const float* head_w2 = (const float*)d_in[16];
    const float* head_b2 = (const float*)d_in[17];
    float* out = (float*)d_out;

    // workspace carve (~65 MB)
    char* p = (char*)d_ws;
    auto alloc = [&](size_t bytes) -> char* {
        char* r = p;
        p += (bytes + 255) & ~size_t(255);
        return r;
    };
    float* h      = (float*)alloc(sizeof(float) * (size_t)N_NODES * HID);
    float* xl     = (float*)alloc(sizeof(float) * (size_t)N_NODES * HID);
    float* xr     = (float*)alloc(sizeof(float) * (size_t)N_NODES * HID);
    int*   deg    = (int*)alloc(4 * (size_t)N_NODES);
    int*   fill   = (int*)alloc(4 * (size_t)N_NODES);
    int*   rowptr = (int*)alloc(4 * (size_t)(N_NODES + 1));
    int*   bsum   = (int*)alloc(4 * 256);
    int2*  csr    = (int2*)alloc(8 * (size_t)N_EDGES);

    const int* srcA = eidx;
    const int* dstA = eidx + N_EDGES;

    int ebl = (N_EDGES + 255) / 256;   // 3125
    int nbl = (N_NODES + 255) / 256;   // 196

    hipMemsetAsync(deg, 0, 4 * (size_t)N_NODES, stream);
    hipMemsetAsync(fill, 0, 4 * (size_t)N_NODES, stream);
    k_count_deg<<<ebl, 256, 0, stream>>>(dstA, deg);
    k_scan_block<<<nbl, 256, 0, stream>>>(deg, rowptr, bsum);
    k_scan_bsum<<<1, 256, 0, stream>>>(bsum, nbl);
    k_scan_add<<<nbl, 256, 0, stream>>>(rowptr, bsum);
    k_scatter<<<ebl, 256, 0, stream>>>(srcA, dstA, rowptr, fill, csr);

    k_proj<<<N_NODES / 16, 192, 0, stream>>>(x, proj_w, proj_b, h);
    for (int l = 0; l < NLAYER; l++) {
        k_lin_lr<<<N_NODES / 16, 192, 0, stream>>>(
            h, lin_l_w + (size_t)l * HID * HID, lin_l_b + (size_t)l * HID,
            lin_r_w + (size_t)l * HID * HID, lin_r_b + (size_t)l * HID, xl, xr);
        k_aggregate<<<N_NODES / 8, 256, 0, stream>>>(
            xl, xr, eattr, rowptr, csr, lin_e_w + (size_t)l * ED * HID,
            att + (size_t)l * HID, conv_b + (size_t)l * HID,
            ln_g + (size_t)l * HID, ln_b + (size_t)l * HID, h);
    }
    k_head<<<(N_NODES + 255) / 256, 256, 0, stream>>>(h, head_w1, head_b1,
                                                      head_w2, head_b2, out);
}

// Round 2
// 957.956 us; speedup vs baseline: 1.2797x; 1.2797x over previous
//
#include <hip/hip_runtime.h>

constexpr int N_NODES = 50000;
constexpr int N_EDGES = 800000;
constexpr int ND  = 32;
constexpr int ED  = 16;
constexpr int HID = 96;
constexpr int NLAYER = 3;

typedef unsigned short ushort_t;
typedef unsigned int uint_t;

__device__ __forceinline__ float bf2f(ushort_t u) {
    union { float f; uint_t ui; } c; c.ui = ((uint_t)u) << 16; return c.f;
}
__device__ __forceinline__ ushort_t f2bf(float f) {
    uint_t u = __float_as_uint(f);
    return (ushort_t)((u + 0x7FFFu + ((u >> 16) & 1u)) >> 16);  // RNE
}

// ---------------- CSR build (by dst), once per call ----------------
__global__ void k_count_deg(const int* __restrict__ dst, int* __restrict__ deg) {
    int e4 = blockIdx.x * 256 + threadIdx.x;
    if (e4 * 4 >= N_EDGES) return;
    int4 d = ((const int4*)dst)[e4];
    atomicAdd(&deg[d.x], 1); atomicAdd(&deg[d.y], 1);
    atomicAdd(&deg[d.z], 1); atomicAdd(&deg[d.w], 1);
}

__global__ void k_scan_block(const int* __restrict__ deg, int* __restrict__ rowptr,
                             int* __restrict__ bsum) {
    __shared__ int s[256];
    int i = blockIdx.x * 256 + threadIdx.x;
    int v = (i < N_NODES) ? deg[i] : 0;
    s[threadIdx.x] = v;
    __syncthreads();
    for (int off = 1; off < 256; off <<= 1) {
        int t = (threadIdx.x >= off) ? s[threadIdx.x - off] : 0;
        __syncthreads();
        s[threadIdx.x] += t;
        __syncthreads();
    }
    if (i < N_NODES) rowptr[i] = s[threadIdx.x] - v;
    if (threadIdx.x == 255) bsum[blockIdx.x] = s[255];
}

__global__ void k_scan_bsum(int* __restrict__ bsum, int nb) {
    __shared__ int s[256];
    int t = threadIdx.x;
    int v = (t < nb) ? bsum[t] : 0;
    s[t] = v;
    __syncthreads();
    for (int off = 1; off < 256; off <<= 1) {
        int tv = (t >= off) ? s[t - off] : 0;
        __syncthreads();
        s[t] += tv;
        __syncthreads();
    }
    if (t < nb) bsum[t] = s[t] - v;
}

__global__ void k_scan_add(int* __restrict__ rowptr, const int* __restrict__ bsum) {
    int i = blockIdx.x * 256 + threadIdx.x;
    if (i < N_NODES) rowptr[i] += bsum[blockIdx.x];
    if (i == 0) rowptr[N_NODES] = N_EDGES;
}

__global__ void k_scatter(const int* __restrict__ src, const int* __restrict__ dst,
                          const int* __restrict__ rowptr, int* __restrict__ fill,
                          int2* __restrict__ csr) {
    int e4 = blockIdx.x * 256 + threadIdx.x;
    if (e4 * 4 >= N_EDGES) return;
    int4 s = ((const int4*)src)[e4];
    int4 d = ((const int4*)dst)[e4];
    int e0 = e4 * 4;
    int p0 = rowptr[d.x] + atomicAdd(&fill[d.x], 1);
    csr[p0] = make_int2(s.x, e0);
    int p1 = rowptr[d.y] + atomicAdd(&fill[d.y], 1);
    csr[p1] = make_int2(s.y, e0 + 1);
    int p2 = rowptr[d.z] + atomicAdd(&fill[d.z], 1);
    csr[p2] = make_int2(s.z, e0 + 2);
    int p3 = rowptr[d.w] + atomicAdd(&fill[d.w], 1);
    csr[p3] = make_int2(s.w, e0 + 3);
}

// ---------------- proj: h = x @ proj_w + proj_b  (K=32) ----------------
__global__ __launch_bounds__(192) void k_proj(const float* __restrict__ x,
                                              const float* __restrict__ pw,
                                              const float* __restrict__ pb,
                                              float* __restrict__ h) {
    int t = threadIdx.x;
    int c = t % 96, half = t / 96;
    float wreg[ND];
#pragma unroll
    for (int k = 0; k < ND; k++) wreg[k] = pw[k * HID + c];
    float b = pb[c];
    int n0 = blockIdx.x * 16 + half * 8;
    for (int i = 0; i < 8; i += 2) {
        int na = n0 + i, nb = na + 1;
        const float4* xa = (const float4*)(x + (size_t)na * ND);
        const float4* xb = (const float4*)(x + (size_t)nb * ND);
        float accA = b, accB = b;
#pragma unroll
        for (int k4 = 0; k4 < ND / 4; k4++) {
            float4 va = xa[k4], vb = xb[k4];
            accA += va.x * wreg[4 * k4] + va.y * wreg[4 * k4 + 1] +
                    va.z * wreg[4 * k4 + 2] + va.w * wreg[4 * k4 + 3];
            accB += vb.x * wreg[4 * k4] + vb.y * wreg[4 * k4 + 1] +
                    vb.z * wreg[4 * k4 + 2] + vb.w * wreg[4 * k4 + 3];
        }
        h[(size_t)na * HID + c] = accA;
        h[(size_t)nb * HID + c] = accB;
    }
}

// ---- xl = h@Wl+bl (bf16 out), xr = h@Wr+br (f32 out); fused, K=96 ----
__global__ __launch_bounds__(192) void k_lin_lr(const float* __restrict__ h,
                                                const float* __restrict__ Wl,
                                                const float* __restrict__ bl,
                                                const float* __restrict__ Wr,
                                                const float* __restrict__ br,
                                                ushort_t* __restrict__ xl,
                                                float* __restrict__ xr) {
    int t = threadIdx.x;
    int c = t % 96, half = t / 96;
    const float* W = half ? Wr : Wl;
    float b = half ? br[c] : bl[c];
    float wreg[HID];
#pragma unroll
    for (int k = 0; k < HID; k++) wreg[k] = W[k * HID + c];
    int n0 = blockIdx.x * 16;
    for (int i = 0; i < 16; i += 2) {
        int na = n0 + i, nb = na + 1;
        const float4* ha = (const float4*)(h + (size_t)na * HID);
        const float4* hb = (const float4*)(h + (size_t)nb * HID);
        float accA = b, accB = b;
#pragma unroll
        for (int k4 = 0; k4 < HID / 4; k4++) {
            float4 va = ha[k4], vb = hb[k4];
            accA += va.x * wreg[4 * k4] + va.y * wreg[4 * k4 + 1] +
                    va.z * wreg[4 * k4 + 2] + va.w * wreg[4 * k4 + 3];
            accB += vb.x * wreg[4 * k4] + vb.y * wreg[4 * k4 + 1] +
                    vb.z * wreg[4 * k4 + 2] + vb.w * wreg[4 * k4 + 3];
        }
        if (half) {
            xr[(size_t)na * HID + c] = accA;
            xr[(size_t)nb * HID + c] = accB;
        } else {
            xl[(size_t)na * HID + c] = f2bf(accA);
            xl[(size_t)nb * HID + c] = f2bf(accB);
        }
    }
}

// ------- fused GATv2 edge pass + softmax + aggregate + residual + LN -------
// One wave (64 lanes) per node; two 32-lane halves take alternating edges
// (serial depth = degree/2). 2-deep software pipeline: next edge's csr entry
// and gathers are issued before computing the current edge. xl is bf16 to
// halve the random-gather footprint. No segment_max needed (logits ~0.2).
__global__ __launch_bounds__(256) void k_aggregate(
    const ushort_t* __restrict__ xlb, const float* __restrict__ xr,
    const float* __restrict__ eattr, const int* __restrict__ rowptr,
    const int2* __restrict__ csr, const float* __restrict__ WeL,
    const float* __restrict__ attL, const float* __restrict__ convb,
    const float* __restrict__ lng, const float* __restrict__ lnb,
    float* __restrict__ h) {
    int t = threadIdx.x;
    int wv = t >> 6;
    int lane = t & 63;
    int half = lane >> 5;
    int sl = lane & 31;
    int node = blockIdx.x * 4 + wv;
    int c0 = sl * 3;

    float we[3 * ED];
#pragma unroll
    for (int k = 0; k < ED; k++) {
#pragma unroll
        for (int j = 0; j < 3; j++) we[k * 3 + j] = WeL[k * HID + c0 + j];
    }
    float at0 = attL[c0], at1 = attL[c0 + 1], at2 = attL[c0 + 2];
    size_t nbase = (size_t)node * HID + c0;
    float xr0 = xr[nbase], xr1 = xr[nbase + 1], xr2 = xr[nbase + 2];

    float num0 = 0.f, num1 = 0.f, num2 = 0.f, den = 0.f;
    int beg = rowptr[node], end = rowptr[node + 1];

    int p = beg + half;
    bool cv = p < end;
    // prologue: load current edge (safe dummy index 0 when invalid)
    int2 se = csr[cv ? p : 0];
    const ushort_t* xp = xlb + (size_t)se.x * HID + c0;
    float cx0 = bf2f(xp[0]), cx1 = bf2f(xp[1]), cx2 = bf2f(xp[2]);
    const float4* ep = (const float4*)(eattr + (size_t)se.y * ED);
    float4 ca0 = ep[0], ca1 = ep[1], ca2 = ep[2], ca3 = ep[3];

    while (cv) {
        // prefetch next edge for this half
        int pn = p + 2;
        bool nv = pn < end;
        int2 sen = csr[nv ? pn : 0];
        const ushort_t* xpn = xlb + (size_t)sen.x * HID + c0;
        ushort_t nu0 = xpn[0], nu1 = xpn[1], nu2 = xpn[2];
        const float4* epn = (const float4*)(eattr + (size_t)sen.y * ED);
        float4 na0 = epn[0], na1 = epn[1], na2 = epn[2], na3 = epn[3];

        // compute current edge
        float ea[16] = {ca0.x, ca0.y, ca0.z, ca0.w, ca1.x, ca1.y, ca1.z, ca1.w,
                        ca2.x, ca2.y, ca2.z, ca2.w, ca3.x, ca3.y, ca3.z, ca3.w};
        float e0 = 0.f, e1 = 0.f, e2 = 0.f;
#pragma unroll
        for (int k = 0; k < ED; k++) {
            e0 += ea[k] * we[k * 3 + 0];
            e1 += ea[k] * we[k * 3 + 1];
            e2 += ea[k] * we[k * 3 + 2];
        }
        float z0 = cx0 + xr0 + e0; z0 = z0 > 0.f ? z0 : 0.2f * z0;
        float z1 = cx1 + xr1 + e1; z1 = z1 > 0.f ? z1 : 0.2f * z1;
        float z2 = cx2 + xr2 + e2; z2 = z2 > 0.f ? z2 : 0.2f * z2;
        float lg = z0 * at0 + z1 * at1 + z2 * at2;
        lg += __shfl_xor(lg, 1);
        lg += __shfl_xor(lg, 2);
        lg += __shfl_xor(lg, 4);   // sum over head's 8 lanes (24 channels)
        float ev = __expf(lg);
        den += ev;
        num0 += ev * cx0; num1 += ev * cx1; num2 += ev * cx2;

        p = pn; cv = nv;
        cx0 = bf2f(nu0); cx1 = bf2f(nu1); cx2 = bf2f(nu2);
        ca0 = na0; ca1 = na1; ca2 = na2; ca3 = na3;
    }

    // combine the two halves
    num0 += __shfl_xor(num0, 32);
    num1 += __shfl_xor(num1, 32);
    num2 += __shfl_xor(num2, 32);
    den  += __shfl_xor(den, 32);

    float inv = 1.f / (den + 1e-16f);
    float v0 = h[nbase]     + num0 * inv + convb[c0];
    float v1 = h[nbase + 1] + num1 * inv + convb[c0 + 1];
    float v2 = h[nbase + 2] + num2 * inv + convb[c0 + 2];
    // LayerNorm over 96 channels = 32 sublanes x 3 (identical in both halves)
    float sm = v0 + v1 + v2;
    sm += __shfl_xor(sm, 1);  sm += __shfl_xor(sm, 2);  sm += __shfl_xor(sm, 4);
    sm += __shfl_xor(sm, 8);  sm += __shfl_xor(sm, 16);
    float mu = sm * (1.f / 96.f);
    float d0 = v0 - mu, d1 = v1 - mu, d2 = v2 - mu;
    float sv = d0 * d0 + d1 * d1 + d2 * d2;
    sv += __shfl_xor(sv, 1);  sv += __shfl_xor(sv, 2);  sv += __shfl_xor(sv, 4);
    sv += __shfl_xor(sv, 8);  sv += __shfl_xor(sv, 16);
    float rstd = rsqrtf(sv * (1.f / 96.f) + 1e-5f);
    if (half == 0) {
        h[nbase]     = d0 * rstd * lng[c0]     + lnb[c0];
        h[nbase + 1] = d1 * rstd * lng[c0 + 1] + lnb[c0 + 1];
        h[nbase + 2] = d2 * rstd * lng[c0 + 2] + lnb[c0 + 2];
    }
}

// ---------------- head: gelu(h@W1+b1)@W2+b2, 4 threads per node ----------------
__global__ __launch_bounds__(256) void k_head(const float* __restrict__ h,
                                              const float* __restrict__ W1,
                                              const float* __restrict__ b1,
                                              const float* __restrict__ W2,
                                              const float* __restrict__ b2,
                                              float* __restrict__ out) {
    int gid = blockIdx.x * 256 + threadIdx.x;
    int n = gid >> 2, q = gid & 3;
    if (n >= N_NODES) return;
    float hr[HID];
    const float4* h4 = (const float4*)(h + (size_t)n * HID);
#pragma unroll
    for (int i = 0; i < HID / 4; i++) {
        float4 v = h4[i];
        hr[4 * i] = v.x; hr[4 * i + 1] = v.y; hr[4 * i + 2] = v.z; hr[4 * i + 3] = v.w;
    }
    const float inv_sqrt2 = 0.70710678118654752f;
    float y = 0.f;
    int j0 = q * 12;
    for (int g = 0; g < 3; g++) {          // 3 groups of 4 hidden units
        int j = j0 + 4 * g;
        float4 acc = make_float4(b1[j], b1[j + 1], b1[j + 2], b1[j + 3]);
#pragma unroll
        for (int k = 0; k < HID; k++) {
            float4 w = *(const float4*)(W1 + k * 48 + j);
            acc.x += hr[k] * w.x; acc.y += hr[k] * w.y;
            acc.z += hr[k] * w.z; acc.w += hr[k] * w.w;
        }
        float g0 = 0.5f * acc.x * (1.f + erff(acc.x * inv_sqrt2));
        float g1 = 0.5f * acc.y * (1.f + erff(acc.y * inv_sqrt2));
        float g2 = 0.5f * acc.z * (1.f + erff(acc.z * inv_sqrt2));
        float g3 = 0.5f * acc.w * (1.f + erff(acc.w * inv_sqrt2));
        y += g0 * W2[j] + g1 * W2[j + 1] + g2 * W2[j + 2] + g3 * W2[j + 3];
    }
    y += __shfl_xor(y, 1);
    y += __shfl_xor(y, 2);
    if (q == 0) out[n] = y + b2[0];
}

extern "C" void kernel_launch(void* const* d_in, const int* in_sizes, int n_in,
                              void* d_out, int out_size, void* d_ws, size_t ws_size,
                              hipStream_t stream) {
    const float* x       = (const float*)d_in[0];
    const int*   eidx    = (const int*)  d_in[1];
    const float* eattr   = (const float*)d_in[2];
    const float* proj_w  = (const float*)d_in[3];
    const float* proj_b  = (const float*)d_in[4];
    const float* lin_l_w = (const float*)d_in[5];
    const float* lin_l_b = (const float*)d_in[6];
    const float* lin_r_w = (const float*)d_in[7];
    const float* lin_r_b = (const float*)d_in[8];
    const float* lin_e_w = (const float*)d_in[9];
    const float* att     = (const float*)d_in[10];
    const float* conv_b  = (const float*)d_in[11];
    const float* ln_g    = (const float*)d_in[12];
    const float* ln_b    = (const float*)d_in[13];
    const float* head_w1 = (const float*)d_in[14];
    const float* head_b1 = (const float*)d_in[15];
    const float* head_w2 = (const float*)d_in[16];
    const float* head_b2 = (const float*)d_in[17];
    float* out = (float*)d_out;

    char* p = (char*)d_ws;
    auto alloc = [&](size_t bytes) -> char* {
        char* r = p;
        p += (bytes + 255) & ~size_t(255);
        return r;
    };
    float*    h      = (float*)alloc(sizeof(float) * (size_t)N_NODES * HID);
    ushort_t* xl     = (ushort_t*)alloc(sizeof(ushort_t) * (size_t)N_NODES * HID);
    float*    xr     = (float*)alloc(sizeof(float) * (size_t)N_NODES * HID);
    int*      deg    = (int*)alloc(4 * (size_t)N_NODES);
    int*      fill   = (int*)alloc(4 * (size_t)N_NODES);
    int*      rowptr = (int*)alloc(4 * (size_t)(N_NODES + 1));
    int*      bsum   = (int*)alloc(4 * 256);
    int2*     csr    = (int2*)alloc(8 * (size_t)N_EDGES);

    const int* srcA = eidx;
    const int* dstA = eidx + N_EDGES;

    int ebl4 = (N_EDGES / 4 + 255) / 256;  // 782 (E divisible by 4)
    int nbl  = (N_NODES + 255) / 256;      // 196

    hipMemsetAsync(deg, 0, 4 * (size_t)N_NODES, stream);
    hipMemsetAsync(fill, 0, 4 * (size_t)N_NODES, stream);
    k_count_deg<<<ebl4, 256, 0, stream>>>(dstA, deg);
    k_scan_block<<<nbl, 256, 0, stream>>>(deg, rowptr, bsum);
    k_scan_bsum<<<1, 256, 0, stream>>>(bsum, nbl);
    k_scan_add<<<nbl, 256, 0, stream>>>(rowptr, bsum);
    k_scatter<<<ebl4, 256, 0, stream>>>(srcA, dstA, rowptr, fill, csr);

    k_proj<<<N_NODES / 16, 192, 0, stream>>>(x, proj_w, proj_b, h);
    for (int l = 0; l < NLAYER; l++) {
        k_lin_lr<<<N_NODES / 16, 192, 0, stream>>>(
            h, lin_l_w + (size_t)l * HID * HID, lin_l_b + (size_t)l * HID,
            lin_r_w + (size_t)l * HID * HID, lin_r_b + (size_t)l * HID, xl, xr);
        k_aggregate<<<N_NODES / 4, 256, 0, stream>>>(
            xl, xr, eattr, rowptr, csr, lin_e_w + (size_t)l * ED * HID,
            att + (size_t)l * HID, conv_b + (size_t)l * HID,
            ln_g + (size_t)l * HID, ln_b + (size_t)l * HID, h);
    }
    k_head<<<(N_NODES * 4 + 255) / 256, 256, 0, stream>>>(h, head_w1, head_b1,
                                                          head_w2, head_b2, out);
}